// Round 14
// baseline (283.428 us; speedup 1.0000x reference)
//
#include <hip/hip_runtime.h>
#include <hip/hip_fp16.h>

// ---------------------------------------------------------------------------
// GCN forward. Key transforms:
//  - dinv folded into features: GEMM epilogue scales row r by dinv[r] (g=hW*dinv);
//    agg computes h_out[c] = relu(dinv[c]*(g[c]+sum g[r]) + b). CSR stores ONLY
//    the 4B source row.
//  - CSR fill is XCD-windowed: block b reads edge chunk b>>3 and keeps only
//    targets in window b&7 -> one XCD owns each CSR slice, stores merge in L2.
//  - The l=2 agg pre-scales its output by dinv (consumer is the layer-4 agg).
//  - W3 commuted past the mean pool (layer-4 GEMM eliminated).
//  - MFMA fp16 GEMMs, fp16 node features, fp32 accumulation everywhere.
//  - Agg (R14): 8 nodes/wave — each 16-lane group runs TWO interleaved node
//    streams (8 gathers in flight vs 4; mean degree 12.8 made single-stream
//    8-deep unroll useless, R11).
// ---------------------------------------------------------------------------

typedef _Float16 half8 __attribute__((ext_vector_type(8)));
typedef float f32x4 __attribute__((ext_vector_type(4)));

__device__ __forceinline__ int idx_at(const void* p, long long i, int is64) {
  return is64 ? (int)((const long long*)p)[i] : ((const int*)p)[i];
}

__global__ void k_detect(const int* __restrict__ edge, int* __restrict__ flag) {
  if (threadIdx.x == 0 && blockIdx.x == 0) {
    int all0 = 1;
    for (int i = 1; i < 128; i += 2)
      if (edge[i] != 0) { all0 = 0; break; }
    *flag = all0;
  }
}

__global__ void k_count(const void* __restrict__ edge, int E,
                        int* __restrict__ cnt, const int* __restrict__ flag) {
  int e = blockIdx.x * 256 + threadIdx.x;
  int is64 = *flag;
  if (e < E) {
    int c = idx_at(edge, (long long)E + e, is64);  // col = target
    atomicAdd(&cnt[c], 1);
  }
}

__global__ void k_dinv(const int* __restrict__ cnt, int n, float* __restrict__ dinv) {
  int i = blockIdx.x * 256 + threadIdx.x;
  if (i < n) dinv[i] = rsqrtf((float)(cnt[i] + 1));  // +1 self loop
}

// --- 3-kernel exclusive scan over cnt[n] -> offs[n] -------------------------
__global__ void k_scan1(const int* __restrict__ cnt, int* __restrict__ offs,
                        int* __restrict__ bsum, int n) {
  __shared__ int lds[256];
  int i = blockIdx.x * 256 + threadIdx.x;
  int v = (i < n) ? cnt[i] : 0;
  lds[threadIdx.x] = v;
  __syncthreads();
  for (int off = 1; off < 256; off <<= 1) {
    int t = (threadIdx.x >= off) ? lds[threadIdx.x - off] : 0;
    __syncthreads();
    lds[threadIdx.x] += t;
    __syncthreads();
  }
  if (i < n) offs[i] = lds[threadIdx.x] - v;
  if (threadIdx.x == 255) bsum[blockIdx.x] = lds[255];
}

__global__ void k_scan2(int* __restrict__ bsum, int nb) {
  __shared__ int lds[256];
  int v = (threadIdx.x < nb) ? bsum[threadIdx.x] : 0;
  lds[threadIdx.x] = v;
  __syncthreads();
  for (int off = 1; off < 256; off <<= 1) {
    int t = (threadIdx.x >= off) ? lds[threadIdx.x - off] : 0;
    __syncthreads();
    lds[threadIdx.x] += t;
    __syncthreads();
  }
  if (threadIdx.x < nb) bsum[threadIdx.x] = lds[threadIdx.x] - v;
}

__global__ void k_scan3(int* __restrict__ offs, int* __restrict__ cursor,
                        const int* __restrict__ bsum, int n, int E) {
  int i = blockIdx.x * 256 + threadIdx.x;
  if (i < n) {
    int o = offs[i] + bsum[blockIdx.x];
    offs[i] = o;
    cursor[i] = o;
  }
  if (i == 0) offs[n] = E;
}

// XCD-windowed CSR fill: block b -> edge chunk (b>>3), target window (b&7).
#define FILL_CH 4096
__global__ __launch_bounds__(256) void k_fill(const void* __restrict__ edge, int E,
                                              int n,
                                              int* __restrict__ cursor,
                                              int* __restrict__ csr_row,
                                              const int* __restrict__ flag) {
  int w = blockIdx.x & 7;
  int chunk = blockIdx.x >> 3;
  int lo = (int)(((long long)w * n) >> 3);
  int hi = (int)(((long long)(w + 1) * n) >> 3);
  int s = chunk * FILL_CH;
  int e_end = s + FILL_CH;
  if (e_end > E) e_end = E;
  int is64 = *flag;
  for (int e = s + threadIdx.x; e < e_end; e += 256) {
    int c = idx_at(edge, (long long)E + e, is64);
    if (c >= lo && c < hi) {
      int r = idx_at(edge, e, is64);
      int p = atomicAdd(&cursor[c], 1);
      csr_row[p] = r;
    }
  }
}

// --- W repack x3: fp32 [k][c] -> fp16 fragment order (one launch) -----------
__global__ void k_wprep3(const float* __restrict__ W0, const float* __restrict__ W1,
                         const float* __restrict__ W2, _Float16* __restrict__ P0,
                         _Float16* __restrict__ P1, _Float16* __restrict__ P2) {
  int t = blockIdx.x * 256 + threadIdx.x;  // 0..49151
  int which = t >> 14;
  int u = t & 16383;
  const float* W = which == 0 ? W0 : (which == 1 ? W1 : W2);
  _Float16* Wp = which == 0 ? P0 : (which == 1 ? P1 : P2);
  int k = u >> 7, c = u & 127;
  int cb = c >> 4, cl = c & 15, ks = k >> 5, kk = k & 31;
  int lane = (kk >> 3) * 16 + cl, j = kk & 7;
  Wp[((cb * 4 + ks) * 64 + lane) * 8 + j] = (_Float16)W[u];
}

// --- MFMA GEMM: C16[r] = (A[r] @ W) * dinv[r], fp16 out ---------------------
__global__ __launch_bounds__(256) void k_gemm16(const _Float16* __restrict__ A16,
                                                const float* __restrict__ A32,
                                                const _Float16* __restrict__ Wp,
                                                const float* __restrict__ dinv,
                                                _Float16* __restrict__ C16, int n) {
  __shared__ float4 Wl[2048];  // 32 KB prepped W
  int t = threadIdx.x;
  const float4* Wp4 = (const float4*)Wp;
#pragma unroll
  for (int i = 0; i < 8; i++) Wl[t + 256 * i] = Wp4[t + 256 * i];
  __syncthreads();
  int wave = t >> 6, l = t & 63;
  int m = blockIdx.x * 64 + wave * 16;
  int lr = l & 15, lg = l >> 4;
  int arow = m + lr;
  if (arow > n - 1) arow = n - 1;  // clamp: stores guarded below
  half8 a[4];
  if (A16) {
#pragma unroll
    for (int ks = 0; ks < 4; ks++)
      a[ks] = *(const half8*)(A16 + (size_t)arow * 128 + ks * 32 + lg * 8);
  } else {
#pragma unroll
    for (int ks = 0; ks < 4; ks++) {
      const float4* s = (const float4*)(A32 + (size_t)arow * 128 + ks * 32 + lg * 8);
      float4 s0 = s[0], s1 = s[1];
      half8 v;
      v[0] = (_Float16)s0.x; v[1] = (_Float16)s0.y;
      v[2] = (_Float16)s0.z; v[3] = (_Float16)s0.w;
      v[4] = (_Float16)s1.x; v[5] = (_Float16)s1.y;
      v[6] = (_Float16)s1.z; v[7] = (_Float16)s1.w;
      a[ks] = v;
    }
  }
  const half8* WlH = (const half8*)Wl;
  f32x4 acc[8];
#pragma unroll
  for (int cb = 0; cb < 8; cb++) {
    f32x4 c = {0.f, 0.f, 0.f, 0.f};
#pragma unroll
    for (int ks = 0; ks < 4; ks++) {
      half8 bfrag = WlH[(cb * 4 + ks) * 64 + l];
      c = __builtin_amdgcn_mfma_f32_16x16x32_f16(a[ks], bfrag, c, 0, 0, 0);
    }
    acc[cb] = c;
  }
#pragma unroll
  for (int i = 0; i < 4; i++) {
    int r = m + lg * 4 + i;
    if (r < n) {
      float sc = dinv[r];
#pragma unroll
      for (int cb = 0; cb < 8; cb++)
        C16[(size_t)r * 128 + cb * 16 + lr] = (_Float16)(acc[cb][i] * sc);
    }
  }
}

// --- Agg: 8 nodes/wave, 2 interleaved streams per 16-lane group -------------
// Input contract: h16[r] is already scaled by dinv[r].
// out = maybe_relu(dinv[c]*(h16[c]+sum h16[r]) + bias); if scale_out, *dinv[c].
__device__ __forceinline__ void add8(float* acc, uint4 r) {
  union { uint4 u; __half2 h[4]; } cv;
  cv.u = r;
#pragma unroll
  for (int q = 0; q < 4; q++) {
    float2 v = __half22float2(cv.h[q]);
    acc[2 * q] += v.x;
    acc[2 * q + 1] += v.y;
  }
}

__device__ __forceinline__ void init_self(float* acc, const uint4* h16,
                                          int node, int sl) {
  uint4 r = h16[(size_t)node * 16 + sl];
  union { uint4 u; __half2 h[4]; } cv;
  cv.u = r;
#pragma unroll
  for (int q = 0; q < 4; q++) {
    float2 v = __half22float2(cv.h[q]);
    acc[2 * q] = v.x;
    acc[2 * q + 1] = v.y;
  }
}

__device__ __forceinline__ void gather4(float* acc, const uint4* __restrict__ h16,
                                        const int* __restrict__ csr_row,
                                        int i, int sl) {
  int r0 = csr_row[i];
  int r1 = csr_row[i + 1];
  int r2 = csr_row[i + 2];
  int r3 = csr_row[i + 3];
  uint4 v0 = h16[(size_t)r0 * 16 + sl];
  uint4 v1 = h16[(size_t)r1 * 16 + sl];
  uint4 v2 = h16[(size_t)r2 * 16 + sl];
  uint4 v3 = h16[(size_t)r3 * 16 + sl];
  add8(acc, v0);
  add8(acc, v1);
  add8(acc, v2);
  add8(acc, v3);
}

__device__ __forceinline__ void agg_epi(float* acc, int node, int sl, float dn,
                                        const float* __restrict__ bias,
                                        uint4* __restrict__ out16,
                                        int relu, int scale_out) {
#pragma unroll
  for (int q = 0; q < 8; q++) acc[q] *= dn;
  if (bias) {
    const float4* b4 = (const float4*)(bias + sl * 8);
    float4 b0 = b4[0], b1 = b4[1];
    acc[0] += b0.x; acc[1] += b0.y; acc[2] += b0.z; acc[3] += b0.w;
    acc[4] += b1.x; acc[5] += b1.y; acc[6] += b1.z; acc[7] += b1.w;
  }
  if (relu) {
#pragma unroll
    for (int q = 0; q < 8; q++) acc[q] = fmaxf(acc[q], 0.f);
  }
  if (scale_out) {
#pragma unroll
    for (int q = 0; q < 8; q++) acc[q] *= dn;
  }
  union { uint4 u; __half2 h[4]; } ov;
#pragma unroll
  for (int q = 0; q < 4; q++)
    ov.h[q] = __floats2half2_rn(acc[2 * q], acc[2 * q + 1]);
  out16[(size_t)node * 16 + sl] = ov.u;
}

__global__ __launch_bounds__(256) void k_agg(const uint4* __restrict__ h16,
                                             const int* __restrict__ offs,
                                             const int* __restrict__ csr_row,
                                             const float* __restrict__ dinv,
                                             const float* __restrict__ bias,
                                             uint4* __restrict__ out16,
                                             int n, int relu, int scale_out) {
  int t = threadIdx.x;
  int wave = t >> 6, l = t & 63;
  int g = l >> 4, sl = l & 15;
  int n0 = blockIdx.x * 32 + wave * 8 + g * 2;
  if (n0 >= n) return;
  int n1 = n0 + 1;
  int has1 = (n1 < n);
  int s0 = offs[n0], e0 = offs[n0 + 1];
  int s1 = has1 ? offs[n1] : 0, e1 = has1 ? offs[n1 + 1] : 0;
  float acc0[8], acc1[8];
  init_self(acc0, h16, n0, sl);
  if (has1) init_self(acc1, h16, n1, sl);
  int i0 = s0, i1 = s1;
  // joint phase: 8 gathers in flight
  while (i0 + 4 <= e0 && i1 + 4 <= e1) {
    int a0 = csr_row[i0], a1 = csr_row[i0 + 1], a2 = csr_row[i0 + 2], a3 = csr_row[i0 + 3];
    int b0 = csr_row[i1], b1 = csr_row[i1 + 1], b2 = csr_row[i1 + 2], b3 = csr_row[i1 + 3];
    uint4 va0 = h16[(size_t)a0 * 16 + sl];
    uint4 va1 = h16[(size_t)a1 * 16 + sl];
    uint4 va2 = h16[(size_t)a2 * 16 + sl];
    uint4 va3 = h16[(size_t)a3 * 16 + sl];
    uint4 vb0 = h16[(size_t)b0 * 16 + sl];
    uint4 vb1 = h16[(size_t)b1 * 16 + sl];
    uint4 vb2 = h16[(size_t)b2 * 16 + sl];
    uint4 vb3 = h16[(size_t)b3 * 16 + sl];
    add8(acc0, va0); add8(acc0, va1); add8(acc0, va2); add8(acc0, va3);
    add8(acc1, vb0); add8(acc1, vb1); add8(acc1, vb2); add8(acc1, vb3);
    i0 += 4; i1 += 4;
  }
  // drain stream 0
  for (; i0 + 4 <= e0; i0 += 4) gather4(acc0, h16, csr_row, i0, sl);
  for (; i0 < e0; i0++) {
    uint4 v = h16[(size_t)csr_row[i0] * 16 + sl];
    add8(acc0, v);
  }
  // drain stream 1
  for (; i1 + 4 <= e1; i1 += 4) gather4(acc1, h16, csr_row, i1, sl);
  for (; i1 < e1; i1++) {
    uint4 v = h16[(size_t)csr_row[i1] * 16 + sl];
    add8(acc1, v);
  }
  agg_epi(acc0, n0, sl, dinv[n0], bias, out16, relu, scale_out);
  if (has1) agg_epi(acc1, n1, sl, dinv[n1], bias, out16, relu, scale_out);
}

// --- Mean pool (fp16 input): chunked partial sums + atomics -----------------
#define POOL_CH 64
__global__ __launch_bounds__(128) void k_pool_partial(
    const _Float16* __restrict__ h, const void* __restrict__ batch, int n,
    float* __restrict__ sums, float* __restrict__ cnts,
    const int* __restrict__ flag) {
  int start = blockIdx.x * POOL_CH;
  if (start >= n) return;
  int end = start + POOL_CH;
  if (end > n) end = n;
  int f = threadIdx.x;  // 128 feature lanes
  int is64 = *flag;
  int g = idx_at(batch, start, is64);
  float acc = 0.f, c = 0.f;
  for (int i = start; i < end; i++) {
    int gi = idx_at(batch, i, is64);
    if (gi != g) {
      atomicAdd(&sums[g * 128 + f], acc);
      if (f == 0) atomicAdd(&cnts[g], c);
      acc = 0.f; c = 0.f; g = gi;
    }
    acc += (float)h[(size_t)i * 128 + f];
    c += 1.f;
  }
  atomicAdd(&sums[g * 128 + f], acc);
  if (f == 0) atomicAdd(&cnts[g], c);
}

// pooled = sums/cnt; t1 = pooled@W3+b3; logits = t1@Wlin+blin; softmax.
__global__ __launch_bounds__(128) void k_final(const float* __restrict__ sums,
                                               const float* __restrict__ cnts,
                                               const float* __restrict__ W3,
                                               const float* __restrict__ b3,
                                               const float* __restrict__ Wlin,
                                               const float* __restrict__ blin,
                                               float* __restrict__ out) {
  __shared__ float p[128];
  __shared__ float t1[128];
  __shared__ float lg[16];
  int g = blockIdx.x;
  int t = threadIdx.x;
  float inv = 1.f / fmaxf(cnts[g], 1.f);
  p[t] = sums[g * 128 + t] * inv;
  __syncthreads();
  float acc = 0.f;
  for (int k = 0; k < 128; k++) acc += p[k] * W3[k * 128 + t];
  t1[t] = acc + b3[t];
  __syncthreads();
  if (t < 16) {
    float a2 = 0.f;
    for (int k = 0; k < 128; k++) a2 += t1[k] * Wlin[k * 16 + t];
    lg[t] = a2 + blin[t];
  }
  __syncthreads();
  if (t < 16) {
    float m = -1e30f;
    for (int j = 0; j < 16; j++) m = fmaxf(m, lg[j]);
    float s = 0.f;
    for (int j = 0; j < 16; j++) s += expf(lg[j] - m);
    out[g * 16 + t] = expf(lg[t] - m) / s;
  }
}

extern "C" void kernel_launch(void* const* d_in, const int* in_sizes, int n_in,
                              void* d_out, int out_size, void* d_ws, size_t ws_size,
                              hipStream_t stream) {
  const float* x = (const float*)d_in[0];
  const void* edge = d_in[1];
  const void* batch = d_in[2];
  const float* W[4] = {(const float*)d_in[3], (const float*)d_in[5],
                       (const float*)d_in[7], (const float*)d_in[9]};
  const float* b[4] = {(const float*)d_in[4], (const float*)d_in[6],
                       (const float*)d_in[8], (const float*)d_in[10]};
  const float* Wlin = (const float*)d_in[11];
  const float* blin = (const float*)d_in[12];
  float* out = (float*)d_out;

  int n = in_sizes[0] / 128;
  int E = in_sizes[1] / 2;
  int ngraphs = out_size / 16;

  char* ws = (char*)d_ws;
  size_t off = 0;
  auto alloc = [&](size_t bytes) -> void* {
    void* p = ws + off;
    off = (off + bytes + 255) & ~(size_t)255;
    return p;
  };
  int* flag = (int*)alloc(4);
  int* cnt = (int*)alloc((size_t)n * 4);
  int* offs = (int*)alloc((size_t)(n + 1) * 4);
  int* cursor = (int*)alloc((size_t)n * 4);
  float* dinv = (float*)alloc((size_t)n * 4);
  int* bsum = (int*)alloc(1024 * 4);
  int* csr_row = (int*)alloc((size_t)E * 4);
  _Float16* Wp0 = (_Float16*)alloc(16384 * 2);
  _Float16* Wp1 = (_Float16*)alloc(16384 * 2);
  _Float16* Wp2 = (_Float16*)alloc(16384 * 2);
  _Float16* hA = (_Float16*)alloc((size_t)n * 128 * 2);  // gemm out / agg3 out
  _Float16* hB = (_Float16*)alloc((size_t)n * 128 * 2);  // agg out (gemm A)
  float* sums = (float*)alloc((size_t)ngraphs * 128 * 4);
  float* cnts = (float*)alloc((size_t)ngraphs * 4);

  hipMemsetAsync(cnt, 0, (size_t)n * 4, stream);
  hipMemsetAsync(sums, 0, (size_t)ngraphs * 128 * 4, stream);
  hipMemsetAsync(cnts, 0, (size_t)ngraphs * 4, stream);
  k_detect<<<1, 64, 0, stream>>>((const int*)edge, flag);
  k_count<<<(E + 255) / 256, 256, 0, stream>>>(edge, E, cnt, flag);
  k_dinv<<<(n + 255) / 256, 256, 0, stream>>>(cnt, n, dinv);
  int nb = (n + 255) / 256;
  k_scan1<<<nb, 256, 0, stream>>>(cnt, offs, bsum, n);
  k_scan2<<<1, 256, 0, stream>>>(bsum, nb);
  k_scan3<<<nb, 256, 0, stream>>>(offs, cursor, bsum, n, E);
  int nchunks = (E + FILL_CH - 1) / FILL_CH;
  k_fill<<<nchunks * 8, 256, 0, stream>>>(edge, E, n, cursor, csr_row, flag);
  k_wprep3<<<192, 256, 0, stream>>>(W[0], W[1], W[2], Wp0, Wp1, Wp2);

  int ngb = (n + 63) / 64;     // gemm blocks (64 rows each)
  int nagg = (n + 31) / 32;    // agg blocks (32 nodes each)
  // layer 0 (A = x fp32, converted in-register)
  k_gemm16<<<ngb, 256, 0, stream>>>(nullptr, x, Wp0, dinv, hA, n);
  k_agg<<<nagg, 256, 0, stream>>>((const uint4*)hA, offs, csr_row, dinv,
                                  b[0], (uint4*)hB, n, 1, 0);
  // layer 1
  k_gemm16<<<ngb, 256, 0, stream>>>(hB, nullptr, Wp1, dinv, hA, n);
  k_agg<<<nagg, 256, 0, stream>>>((const uint4*)hA, offs, csr_row, dinv,
                                  b[1], (uint4*)hB, n, 1, 0);
  // layer 2: output h3 consumed only by the layer-4 agg -> pre-scale by dinv
  k_gemm16<<<ngb, 256, 0, stream>>>(hB, nullptr, Wp2, dinv, hA, n);
  k_agg<<<nagg, 256, 0, stream>>>((const uint4*)hA, offs, csr_row, dinv,
                                  b[2], (uint4*)hB, n, 1, 1);
  // layer 4 agg (no bias/relu, raw output); W3+b3 applied post-pool in k_final
  k_agg<<<nagg, 256, 0, stream>>>((const uint4*)hB, offs, csr_row, dinv,
                                  nullptr, (uint4*)hA, n, 0, 0);
  k_pool_partial<<<(n + POOL_CH - 1) / POOL_CH, 128, 0, stream>>>(hA, batch, n, sums, cnts, flag);
  k_final<<<ngraphs, 128, 0, stream>>>(sums, cnts, W[3], b[3], Wlin, blin, out);
}

// Round 15
// 261.667 us; speedup vs baseline: 1.0832x; 1.0832x over previous
//
#include <hip/hip_runtime.h>
#include <hip/hip_fp16.h>

// ---------------------------------------------------------------------------
// GCN forward. Key transforms:
//  - dinv folded into features: GEMM epilogue scales row r by dinv[r] (g=hW*dinv);
//    agg computes h_out[c] = relu(dinv[c]*(g[c]+sum g[r]) + b). CSR stores ONLY
//    the 4B source row.
//  - CSR fill is XCD-windowed: block b reads edge chunk b>>3 and keeps only
//    targets in window b&7 -> one XCD owns each CSR slice, stores merge in L2.
//  - The l=2 agg pre-scales its output by dinv (consumer is the layer-4 agg).
//  - W3 commuted past the mean pool (layer-4 GEMM eliminated).
//  - MFMA fp16 GEMMs, fp16 node features, fp32 accumulation everywhere.
//  - Agg (R15 = best measured combo): 4 nodes/wave, 16 lanes/node, 16B/lane,
//    single-stream 8-deep pipeline (R11's agg — R13 revert cost ~24us; R14's
//    two-stream variant lost to VGPR pressure).
// ---------------------------------------------------------------------------

typedef _Float16 half8 __attribute__((ext_vector_type(8)));
typedef float f32x4 __attribute__((ext_vector_type(4)));

__device__ __forceinline__ int idx_at(const void* p, long long i, int is64) {
  return is64 ? (int)((const long long*)p)[i] : ((const int*)p)[i];
}

__global__ void k_detect(const int* __restrict__ edge, int* __restrict__ flag) {
  if (threadIdx.x == 0 && blockIdx.x == 0) {
    int all0 = 1;
    for (int i = 1; i < 128; i += 2)
      if (edge[i] != 0) { all0 = 0; break; }
    *flag = all0;
  }
}

__global__ void k_count(const void* __restrict__ edge, int E,
                        int* __restrict__ cnt, const int* __restrict__ flag) {
  int e = blockIdx.x * 256 + threadIdx.x;
  int is64 = *flag;
  if (e < E) {
    int c = idx_at(edge, (long long)E + e, is64);  // col = target
    atomicAdd(&cnt[c], 1);
  }
}

__global__ void k_dinv(const int* __restrict__ cnt, int n, float* __restrict__ dinv) {
  int i = blockIdx.x * 256 + threadIdx.x;
  if (i < n) dinv[i] = rsqrtf((float)(cnt[i] + 1));  // +1 self loop
}

// --- 3-kernel exclusive scan over cnt[n] -> offs[n] -------------------------
__global__ void k_scan1(const int* __restrict__ cnt, int* __restrict__ offs,
                        int* __restrict__ bsum, int n) {
  __shared__ int lds[256];
  int i = blockIdx.x * 256 + threadIdx.x;
  int v = (i < n) ? cnt[i] : 0;
  lds[threadIdx.x] = v;
  __syncthreads();
  for (int off = 1; off < 256; off <<= 1) {
    int t = (threadIdx.x >= off) ? lds[threadIdx.x - off] : 0;
    __syncthreads();
    lds[threadIdx.x] += t;
    __syncthreads();
  }
  if (i < n) offs[i] = lds[threadIdx.x] - v;
  if (threadIdx.x == 255) bsum[blockIdx.x] = lds[255];
}

__global__ void k_scan2(int* __restrict__ bsum, int nb) {
  __shared__ int lds[256];
  int v = (threadIdx.x < nb) ? bsum[threadIdx.x] : 0;
  lds[threadIdx.x] = v;
  __syncthreads();
  for (int off = 1; off < 256; off <<= 1) {
    int t = (threadIdx.x >= off) ? lds[threadIdx.x - off] : 0;
    __syncthreads();
    lds[threadIdx.x] += t;
    __syncthreads();
  }
  if (threadIdx.x < nb) bsum[threadIdx.x] = lds[threadIdx.x] - v;
}

__global__ void k_scan3(int* __restrict__ offs, int* __restrict__ cursor,
                        const int* __restrict__ bsum, int n, int E) {
  int i = blockIdx.x * 256 + threadIdx.x;
  if (i < n) {
    int o = offs[i] + bsum[blockIdx.x];
    offs[i] = o;
    cursor[i] = o;
  }
  if (i == 0) offs[n] = E;
}

// XCD-windowed CSR fill: block b -> edge chunk (b>>3), target window (b&7).
#define FILL_CH 4096
__global__ __launch_bounds__(256) void k_fill(const void* __restrict__ edge, int E,
                                              int n,
                                              int* __restrict__ cursor,
                                              int* __restrict__ csr_row,
                                              const int* __restrict__ flag) {
  int w = blockIdx.x & 7;
  int chunk = blockIdx.x >> 3;
  int lo = (int)(((long long)w * n) >> 3);
  int hi = (int)(((long long)(w + 1) * n) >> 3);
  int s = chunk * FILL_CH;
  int e_end = s + FILL_CH;
  if (e_end > E) e_end = E;
  int is64 = *flag;
  for (int e = s + threadIdx.x; e < e_end; e += 256) {
    int c = idx_at(edge, (long long)E + e, is64);
    if (c >= lo && c < hi) {
      int r = idx_at(edge, e, is64);
      int p = atomicAdd(&cursor[c], 1);
      csr_row[p] = r;
    }
  }
}

// --- W repack x3: fp32 [k][c] -> fp16 fragment order (one launch) -----------
__global__ void k_wprep3(const float* __restrict__ W0, const float* __restrict__ W1,
                         const float* __restrict__ W2, _Float16* __restrict__ P0,
                         _Float16* __restrict__ P1, _Float16* __restrict__ P2) {
  int t = blockIdx.x * 256 + threadIdx.x;  // 0..49151
  int which = t >> 14;
  int u = t & 16383;
  const float* W = which == 0 ? W0 : (which == 1 ? W1 : W2);
  _Float16* Wp = which == 0 ? P0 : (which == 1 ? P1 : P2);
  int k = u >> 7, c = u & 127;
  int cb = c >> 4, cl = c & 15, ks = k >> 5, kk = k & 31;
  int lane = (kk >> 3) * 16 + cl, j = kk & 7;
  Wp[((cb * 4 + ks) * 64 + lane) * 8 + j] = (_Float16)W[u];
}

// --- MFMA GEMM: C16[r] = (A[r] @ W) * dinv[r], fp16 out ---------------------
__global__ __launch_bounds__(256) void k_gemm16(const _Float16* __restrict__ A16,
                                                const float* __restrict__ A32,
                                                const _Float16* __restrict__ Wp,
                                                const float* __restrict__ dinv,
                                                _Float16* __restrict__ C16, int n) {
  __shared__ float4 Wl[2048];  // 32 KB prepped W
  int t = threadIdx.x;
  const float4* Wp4 = (const float4*)Wp;
#pragma unroll
  for (int i = 0; i < 8; i++) Wl[t + 256 * i] = Wp4[t + 256 * i];
  __syncthreads();
  int wave = t >> 6, l = t & 63;
  int m = blockIdx.x * 64 + wave * 16;
  int lr = l & 15, lg = l >> 4;
  int arow = m + lr;
  if (arow > n - 1) arow = n - 1;  // clamp: stores guarded below
  half8 a[4];
  if (A16) {
#pragma unroll
    for (int ks = 0; ks < 4; ks++)
      a[ks] = *(const half8*)(A16 + (size_t)arow * 128 + ks * 32 + lg * 8);
  } else {
#pragma unroll
    for (int ks = 0; ks < 4; ks++) {
      const float4* s = (const float4*)(A32 + (size_t)arow * 128 + ks * 32 + lg * 8);
      float4 s0 = s[0], s1 = s[1];
      half8 v;
      v[0] = (_Float16)s0.x; v[1] = (_Float16)s0.y;
      v[2] = (_Float16)s0.z; v[3] = (_Float16)s0.w;
      v[4] = (_Float16)s1.x; v[5] = (_Float16)s1.y;
      v[6] = (_Float16)s1.z; v[7] = (_Float16)s1.w;
      a[ks] = v;
    }
  }
  const half8* WlH = (const half8*)Wl;
  f32x4 acc[8];
#pragma unroll
  for (int cb = 0; cb < 8; cb++) {
    f32x4 c = {0.f, 0.f, 0.f, 0.f};
#pragma unroll
    for (int ks = 0; ks < 4; ks++) {
      half8 bfrag = WlH[(cb * 4 + ks) * 64 + l];
      c = __builtin_amdgcn_mfma_f32_16x16x32_f16(a[ks], bfrag, c, 0, 0, 0);
    }
    acc[cb] = c;
  }
#pragma unroll
  for (int i = 0; i < 4; i++) {
    int r = m + lg * 4 + i;
    if (r < n) {
      float sc = dinv[r];
#pragma unroll
      for (int cb = 0; cb < 8; cb++)
        C16[(size_t)r * 128 + cb * 16 + lr] = (_Float16)(acc[cb][i] * sc);
    }
  }
}

// --- Agg: 4 nodes/wave, 16 lanes/node, 16B/lane, 8-deep pipeline ------------
// Input contract: h16[r] is already scaled by dinv[r].
// out = maybe_relu(dinv[c]*(h16[c]+sum h16[r]) + bias); if scale_out, *dinv[c].
__device__ __forceinline__ void add8(float* acc, uint4 r) {
  union { uint4 u; __half2 h[4]; } cv;
  cv.u = r;
#pragma unroll
  for (int q = 0; q < 4; q++) {
    float2 v = __half22float2(cv.h[q]);
    acc[2 * q] += v.x;
    acc[2 * q + 1] += v.y;
  }
}

__global__ __launch_bounds__(256) void k_agg(const uint4* __restrict__ h16,
                                             const int* __restrict__ offs,
                                             const int* __restrict__ csr_row,
                                             const float* __restrict__ dinv,
                                             const float* __restrict__ bias,
                                             uint4* __restrict__ out16,
                                             int n, int relu, int scale_out) {
  int t = threadIdx.x;
  int wave = t >> 6, l = t & 63;
  int g = l >> 4, sl = l & 15;
  int node = blockIdx.x * 16 + wave * 4 + g;
  if (node >= n) return;
  int s = offs[node], e = offs[node + 1];
  float acc[8];
  {  // self term g[c]
    uint4 r = h16[(size_t)node * 16 + sl];
    union { uint4 u; __half2 h[4]; } cv;
    cv.u = r;
#pragma unroll
    for (int q = 0; q < 4; q++) {
      float2 v = __half22float2(cv.h[q]);
      acc[2 * q] = v.x;
      acc[2 * q + 1] = v.y;
    }
  }
  int i = s;
  for (; i + 8 <= e; i += 8) {
    int r0 = csr_row[i];
    int r1 = csr_row[i + 1];
    int r2 = csr_row[i + 2];
    int r3 = csr_row[i + 3];
    int r4 = csr_row[i + 4];
    int r5 = csr_row[i + 5];
    int r6 = csr_row[i + 6];
    int r7 = csr_row[i + 7];
    uint4 v0 = h16[(size_t)r0 * 16 + sl];
    uint4 v1 = h16[(size_t)r1 * 16 + sl];
    uint4 v2 = h16[(size_t)r2 * 16 + sl];
    uint4 v3 = h16[(size_t)r3 * 16 + sl];
    uint4 v4 = h16[(size_t)r4 * 16 + sl];
    uint4 v5 = h16[(size_t)r5 * 16 + sl];
    uint4 v6 = h16[(size_t)r6 * 16 + sl];
    uint4 v7 = h16[(size_t)r7 * 16 + sl];
    add8(acc, v0);
    add8(acc, v1);
    add8(acc, v2);
    add8(acc, v3);
    add8(acc, v4);
    add8(acc, v5);
    add8(acc, v6);
    add8(acc, v7);
  }
  for (; i + 4 <= e; i += 4) {
    int r0 = csr_row[i];
    int r1 = csr_row[i + 1];
    int r2 = csr_row[i + 2];
    int r3 = csr_row[i + 3];
    uint4 v0 = h16[(size_t)r0 * 16 + sl];
    uint4 v1 = h16[(size_t)r1 * 16 + sl];
    uint4 v2 = h16[(size_t)r2 * 16 + sl];
    uint4 v3 = h16[(size_t)r3 * 16 + sl];
    add8(acc, v0);
    add8(acc, v1);
    add8(acc, v2);
    add8(acc, v3);
  }
  for (; i < e; i++) {
    uint4 v = h16[(size_t)csr_row[i] * 16 + sl];
    add8(acc, v);
  }
  float dn = dinv[node];
#pragma unroll
  for (int q = 0; q < 8; q++) acc[q] *= dn;
  if (bias) {
    const float4* b4 = (const float4*)(bias + sl * 8);
    float4 b0 = b4[0], b1 = b4[1];
    acc[0] += b0.x; acc[1] += b0.y; acc[2] += b0.z; acc[3] += b0.w;
    acc[4] += b1.x; acc[5] += b1.y; acc[6] += b1.z; acc[7] += b1.w;
  }
  if (relu) {
#pragma unroll
    for (int q = 0; q < 8; q++) acc[q] = fmaxf(acc[q], 0.f);
  }
  if (scale_out) {
#pragma unroll
    for (int q = 0; q < 8; q++) acc[q] *= dn;
  }
  union { uint4 u; __half2 h[4]; } ov;
#pragma unroll
  for (int q = 0; q < 4; q++)
    ov.h[q] = __floats2half2_rn(acc[2 * q], acc[2 * q + 1]);
  out16[(size_t)node * 16 + sl] = ov.u;
}

// --- Mean pool (fp16 input): chunked partial sums + atomics -----------------
#define POOL_CH 64
__global__ __launch_bounds__(128) void k_pool_partial(
    const _Float16* __restrict__ h, const void* __restrict__ batch, int n,
    float* __restrict__ sums, float* __restrict__ cnts,
    const int* __restrict__ flag) {
  int start = blockIdx.x * POOL_CH;
  if (start >= n) return;
  int end = start + POOL_CH;
  if (end > n) end = n;
  int f = threadIdx.x;  // 128 feature lanes
  int is64 = *flag;
  int g = idx_at(batch, start, is64);
  float acc = 0.f, c = 0.f;
  for (int i = start; i < end; i++) {
    int gi = idx_at(batch, i, is64);
    if (gi != g) {
      atomicAdd(&sums[g * 128 + f], acc);
      if (f == 0) atomicAdd(&cnts[g], c);
      acc = 0.f; c = 0.f; g = gi;
    }
    acc += (float)h[(size_t)i * 128 + f];
    c += 1.f;
  }
  atomicAdd(&sums[g * 128 + f], acc);
  if (f == 0) atomicAdd(&cnts[g], c);
}

// pooled = sums/cnt; t1 = pooled@W3+b3; logits = t1@Wlin+blin; softmax.
__global__ __launch_bounds__(128) void k_final(const float* __restrict__ sums,
                                               const float* __restrict__ cnts,
                                               const float* __restrict__ W3,
                                               const float* __restrict__ b3,
                                               const float* __restrict__ Wlin,
                                               const float* __restrict__ blin,
                                               float* __restrict__ out) {
  __shared__ float p[128];
  __shared__ float t1[128];
  __shared__ float lg[16];
  int g = blockIdx.x;
  int t = threadIdx.x;
  float inv = 1.f / fmaxf(cnts[g], 1.f);
  p[t] = sums[g * 128 + t] * inv;
  __syncthreads();
  float acc = 0.f;
  for (int k = 0; k < 128; k++) acc += p[k] * W3[k * 128 + t];
  t1[t] = acc + b3[t];
  __syncthreads();
  if (t < 16) {
    float a2 = 0.f;
    for (int k = 0; k < 128; k++) a2 += t1[k] * Wlin[k * 16 + t];
    lg[t] = a2 + blin[t];
  }
  __syncthreads();
  if (t < 16) {
    float m = -1e30f;
    for (int j = 0; j < 16; j++) m = fmaxf(m, lg[j]);
    float s = 0.f;
    for (int j = 0; j < 16; j++) s += expf(lg[j] - m);
    out[g * 16 + t] = expf(lg[t] - m) / s;
  }
}

extern "C" void kernel_launch(void* const* d_in, const int* in_sizes, int n_in,
                              void* d_out, int out_size, void* d_ws, size_t ws_size,
                              hipStream_t stream) {
  const float* x = (const float*)d_in[0];
  const void* edge = d_in[1];
  const void* batch = d_in[2];
  const float* W[4] = {(const float*)d_in[3], (const float*)d_in[5],
                       (const float*)d_in[7], (const float*)d_in[9]};
  const float* b[4] = {(const float*)d_in[4], (const float*)d_in[6],
                       (const float*)d_in[8], (const float*)d_in[10]};
  const float* Wlin = (const float*)d_in[11];
  const float* blin = (const float*)d_in[12];
  float* out = (float*)d_out;

  int n = in_sizes[0] / 128;
  int E = in_sizes[1] / 2;
  int ngraphs = out_size / 16;

  char* ws = (char*)d_ws;
  size_t off = 0;
  auto alloc = [&](size_t bytes) -> void* {
    void* p = ws + off;
    off = (off + bytes + 255) & ~(size_t)255;
    return p;
  };
  int* flag = (int*)alloc(4);
  int* cnt = (int*)alloc((size_t)n * 4);
  int* offs = (int*)alloc((size_t)(n + 1) * 4);
  int* cursor = (int*)alloc((size_t)n * 4);
  float* dinv = (float*)alloc((size_t)n * 4);
  int* bsum = (int*)alloc(1024 * 4);
  int* csr_row = (int*)alloc((size_t)E * 4);
  _Float16* Wp0 = (_Float16*)alloc(16384 * 2);
  _Float16* Wp1 = (_Float16*)alloc(16384 * 2);
  _Float16* Wp2 = (_Float16*)alloc(16384 * 2);
  _Float16* hA = (_Float16*)alloc((size_t)n * 128 * 2);  // gemm out / agg3 out
  _Float16* hB = (_Float16*)alloc((size_t)n * 128 * 2);  // agg out (gemm A)
  float* sums = (float*)alloc((size_t)ngraphs * 128 * 4);
  float* cnts = (float*)alloc((size_t)ngraphs * 4);

  hipMemsetAsync(cnt, 0, (size_t)n * 4, stream);
  hipMemsetAsync(sums, 0, (size_t)ngraphs * 128 * 4, stream);
  hipMemsetAsync(cnts, 0, (size_t)ngraphs * 4, stream);
  k_detect<<<1, 64, 0, stream>>>((const int*)edge, flag);
  k_count<<<(E + 255) / 256, 256, 0, stream>>>(edge, E, cnt, flag);
  k_dinv<<<(n + 255) / 256, 256, 0, stream>>>(cnt, n, dinv);
  int nb = (n + 255) / 256;
  k_scan1<<<nb, 256, 0, stream>>>(cnt, offs, bsum, n);
  k_scan2<<<1, 256, 0, stream>>>(bsum, nb);
  k_scan3<<<nb, 256, 0, stream>>>(offs, cursor, bsum, n, E);
  int nchunks = (E + FILL_CH - 1) / FILL_CH;
  k_fill<<<nchunks * 8, 256, 0, stream>>>(edge, E, n, cursor, csr_row, flag);
  k_wprep3<<<192, 256, 0, stream>>>(W[0], W[1], W[2], Wp0, Wp1, Wp2);

  int ngb = (n + 63) / 64;     // gemm blocks (64 rows each)
  int nagg = (n + 15) / 16;    // agg blocks (16 nodes each)
  // layer 0 (A = x fp32, converted in-register)
  k_gemm16<<<ngb, 256, 0, stream>>>(nullptr, x, Wp0, dinv, hA, n);
  k_agg<<<nagg, 256, 0, stream>>>((const uint4*)hA, offs, csr_row, dinv,
                                  b[0], (uint4*)hB, n, 1, 0);
  // layer 1
  k_gemm16<<<ngb, 256, 0, stream>>>(hB, nullptr, Wp1, dinv, hA, n);
  k_agg<<<nagg, 256, 0, stream>>>((const uint4*)hA, offs, csr_row, dinv,
                                  b[1], (uint4*)hB, n, 1, 0);
  // layer 2: output h3 consumed only by the layer-4 agg -> pre-scale by dinv
  k_gemm16<<<ngb, 256, 0, stream>>>(hB, nullptr, Wp2, dinv, hA, n);
  k_agg<<<nagg, 256, 0, stream>>>((const uint4*)hA, offs, csr_row, dinv,
                                  b[2], (uint4*)hB, n, 1, 1);
  // layer 4 agg (no bias/relu, raw output); W3+b3 applied post-pool in k_final
  k_agg<<<nagg, 256, 0, stream>>>((const uint4*)hB, offs, csr_row, dinv,
                                  nullptr, (uint4*)hA, n, 0, 0);
  k_pool_partial<<<(n + POOL_CH - 1) / POOL_CH, 128, 0, stream>>>(hA, batch, n, sums, cnts, flag);
  k_final<<<ngraphs, 128, 0, stream>>>(sums, cnts, W[3], b[3], Wlin, blin, out);
}

// Round 16
// 229.625 us; speedup vs baseline: 1.2343x; 1.1395x over previous
//
#include <hip/hip_runtime.h>
#include <hip/hip_fp16.h>

// ---------------------------------------------------------------------------
// GCN forward. Key transforms (cumulative):
//  - dinv folded into features; CSR stores only the 4B source row.
//  - XCD-windowed CSR fill (one XCD owns each CSR slice -> stores merge in L2).
//  - W3 commuted past the mean pool (layer-4 GEMM eliminated).
//  - MFMA fp16 GEMMs, fp32 accumulation everywhere.
//  - R16: GEMM outputs g_l stored FP8 e4m3 (the 3 gather-heavy buffers);
//    agg outputs h_l stay fp16 (sequential readers only; no fresh fp8 on h).
//    Halves the agg gather's L2-miss traffic; error bounded ~1e-4 at output.
// ---------------------------------------------------------------------------

typedef _Float16 half8 __attribute__((ext_vector_type(8)));
typedef float f32x4 __attribute__((ext_vector_type(4)));
typedef float floatx2 __attribute__((ext_vector_type(2)));

__device__ __forceinline__ int idx_at(const void* p, long long i, int is64) {
  return is64 ? (int)((const long long*)p)[i] : ((const int*)p)[i];
}

__global__ void k_detect(const int* __restrict__ edge, int* __restrict__ flag) {
  if (threadIdx.x == 0 && blockIdx.x == 0) {
    int all0 = 1;
    for (int i = 1; i < 128; i += 2)
      if (edge[i] != 0) { all0 = 0; break; }
    *flag = all0;
  }
}

__global__ void k_count(const void* __restrict__ edge, int E,
                        int* __restrict__ cnt, const int* __restrict__ flag) {
  int e = blockIdx.x * 256 + threadIdx.x;
  int is64 = *flag;
  if (e < E) {
    int c = idx_at(edge, (long long)E + e, is64);  // col = target
    atomicAdd(&cnt[c], 1);
  }
}

__global__ void k_dinv(const int* __restrict__ cnt, int n, float* __restrict__ dinv) {
  int i = blockIdx.x * 256 + threadIdx.x;
  if (i < n) dinv[i] = rsqrtf((float)(cnt[i] + 1));  // +1 self loop
}

// --- 3-kernel exclusive scan over cnt[n] -> offs[n] -------------------------
__global__ void k_scan1(const int* __restrict__ cnt, int* __restrict__ offs,
                        int* __restrict__ bsum, int n) {
  __shared__ int lds[256];
  int i = blockIdx.x * 256 + threadIdx.x;
  int v = (i < n) ? cnt[i] : 0;
  lds[threadIdx.x] = v;
  __syncthreads();
  for (int off = 1; off < 256; off <<= 1) {
    int t = (threadIdx.x >= off) ? lds[threadIdx.x - off] : 0;
    __syncthreads();
    lds[threadIdx.x] += t;
    __syncthreads();
  }
  if (i < n) offs[i] = lds[threadIdx.x] - v;
  if (threadIdx.x == 255) bsum[blockIdx.x] = lds[255];
}

__global__ void k_scan2(int* __restrict__ bsum, int nb) {
  __shared__ int lds[256];
  int v = (threadIdx.x < nb) ? bsum[threadIdx.x] : 0;
  lds[threadIdx.x] = v;
  __syncthreads();
  for (int off = 1; off < 256; off <<= 1) {
    int t = (threadIdx.x >= off) ? lds[threadIdx.x - off] : 0;
    __syncthreads();
    lds[threadIdx.x] += t;
    __syncthreads();
  }
  if (threadIdx.x < nb) bsum[threadIdx.x] = lds[threadIdx.x] - v;
}

__global__ void k_scan3(int* __restrict__ offs, int* __restrict__ cursor,
                        const int* __restrict__ bsum, int n, int E) {
  int i = blockIdx.x * 256 + threadIdx.x;
  if (i < n) {
    int o = offs[i] + bsum[blockIdx.x];
    offs[i] = o;
    cursor[i] = o;
  }
  if (i == 0) offs[n] = E;
}

// XCD-windowed CSR fill: block b -> edge chunk (b>>3), target window (b&7).
#define FILL_CH 4096
__global__ __launch_bounds__(256) void k_fill(const void* __restrict__ edge, int E,
                                              int n,
                                              int* __restrict__ cursor,
                                              int* __restrict__ csr_row,
                                              const int* __restrict__ flag) {
  int w = blockIdx.x & 7;
  int chunk = blockIdx.x >> 3;
  int lo = (int)(((long long)w * n) >> 3);
  int hi = (int)(((long long)(w + 1) * n) >> 3);
  int s = chunk * FILL_CH;
  int e_end = s + FILL_CH;
  if (e_end > E) e_end = E;
  int is64 = *flag;
  for (int e = s + threadIdx.x; e < e_end; e += 256) {
    int c = idx_at(edge, (long long)E + e, is64);
    if (c >= lo && c < hi) {
      int r = idx_at(edge, e, is64);
      int p = atomicAdd(&cursor[c], 1);
      csr_row[p] = r;
    }
  }
}

// --- W repack x3: fp32 [k][c] -> fp16 fragment order (one launch) -----------
__global__ void k_wprep3(const float* __restrict__ W0, const float* __restrict__ W1,
                         const float* __restrict__ W2, _Float16* __restrict__ P0,
                         _Float16* __restrict__ P1, _Float16* __restrict__ P2) {
  int t = blockIdx.x * 256 + threadIdx.x;  // 0..49151
  int which = t >> 14;
  int u = t & 16383;
  const float* W = which == 0 ? W0 : (which == 1 ? W1 : W2);
  _Float16* Wp = which == 0 ? P0 : (which == 1 ? P1 : P2);
  int k = u >> 7, c = u & 127;
  int cb = c >> 4, cl = c & 15, ks = k >> 5, kk = k & 31;
  int lane = (kk >> 3) * 16 + cl, j = kk & 7;
  Wp[((cb * 4 + ks) * 64 + lane) * 8 + j] = (_Float16)W[u];
}

// --- MFMA GEMM: C8[r] = fp8_e4m3((A[r] @ W) * dinv[r]) ----------------------
__global__ __launch_bounds__(256) void k_gemm16(const _Float16* __restrict__ A16,
                                                const float* __restrict__ A32,
                                                const _Float16* __restrict__ Wp,
                                                const float* __restrict__ dinv,
                                                unsigned char* __restrict__ C8,
                                                int n) {
  __shared__ float4 Wl[2048];  // 32 KB prepped W
  int t = threadIdx.x;
  const float4* Wp4 = (const float4*)Wp;
#pragma unroll
  for (int i = 0; i < 8; i++) Wl[t + 256 * i] = Wp4[t + 256 * i];
  __syncthreads();
  int wave = t >> 6, l = t & 63;
  int m = blockIdx.x * 64 + wave * 16;
  int lr = l & 15, lg = l >> 4;
  int arow = m + lr;
  if (arow > n - 1) arow = n - 1;  // clamp: stores guarded below
  half8 a[4];
  if (A16) {
#pragma unroll
    for (int ks = 0; ks < 4; ks++)
      a[ks] = *(const half8*)(A16 + (size_t)arow * 128 + ks * 32 + lg * 8);
  } else {
#pragma unroll
    for (int ks = 0; ks < 4; ks++) {
      const float4* s = (const float4*)(A32 + (size_t)arow * 128 + ks * 32 + lg * 8);
      float4 s0 = s[0], s1 = s[1];
      half8 v;
      v[0] = (_Float16)s0.x; v[1] = (_Float16)s0.y;
      v[2] = (_Float16)s0.z; v[3] = (_Float16)s0.w;
      v[4] = (_Float16)s1.x; v[5] = (_Float16)s1.y;
      v[6] = (_Float16)s1.z; v[7] = (_Float16)s1.w;
      a[ks] = v;
    }
  }
  const half8* WlH = (const half8*)Wl;
  f32x4 acc[8];
#pragma unroll
  for (int cb = 0; cb < 8; cb++) {
    f32x4 c = {0.f, 0.f, 0.f, 0.f};
#pragma unroll
    for (int ks = 0; ks < 4; ks++) {
      half8 bfrag = WlH[(cb * 4 + ks) * 64 + l];
      c = __builtin_amdgcn_mfma_f32_16x16x32_f16(a[ks], bfrag, c, 0, 0, 0);
    }
    acc[cb] = c;
  }
#pragma unroll
  for (int i = 0; i < 4; i++) {
    int r = m + lg * 4 + i;
    if (r < n) {
      float sc = dinv[r];
#pragma unroll
      for (int cb = 0; cb < 8; cb++) {
        float v = acc[cb][i] * sc;
        unsigned int pk = __builtin_amdgcn_cvt_pk_fp8_f32(v, v, 0, false);
        C8[(size_t)r * 128 + cb * 16 + lr] = (unsigned char)(pk & 0xff);
      }
    }
  }
}

// --- Agg (fp8 input): 4 nodes/wave, 16 lanes/node, 8B/lane, 8-deep ----------
// Input contract: g8[r] = fp8(g scaled by dinv[r]).
// out16 = fp16( maybe_relu(dinv[c]*(g[c]+sum g[r]) + bias) [ *dinv[c] ] ).
__device__ __forceinline__ void add8_fp8(float* acc, uint2 v) {
  floatx2 p0 = __builtin_amdgcn_cvt_pk_f32_fp8((int)v.x, false);
  floatx2 p1 = __builtin_amdgcn_cvt_pk_f32_fp8((int)v.x, true);
  floatx2 p2 = __builtin_amdgcn_cvt_pk_f32_fp8((int)v.y, false);
  floatx2 p3 = __builtin_amdgcn_cvt_pk_f32_fp8((int)v.y, true);
  acc[0] += p0.x; acc[1] += p0.y; acc[2] += p1.x; acc[3] += p1.y;
  acc[4] += p2.x; acc[5] += p2.y; acc[6] += p3.x; acc[7] += p3.y;
}

__global__ __launch_bounds__(256) void k_agg_fp8(const uint2* __restrict__ g8,
                                                 const int* __restrict__ offs,
                                                 const int* __restrict__ csr_row,
                                                 const float* __restrict__ dinv,
                                                 const float* __restrict__ bias,
                                                 uint4* __restrict__ out16,
                                                 int n, int relu, int scale_out) {
  int t = threadIdx.x;
  int wave = t >> 6, l = t & 63;
  int g = l >> 4, sl = l & 15;
  int node = blockIdx.x * 16 + wave * 4 + g;
  if (node >= n) return;
  int s = offs[node], e = offs[node + 1];
  float acc[8];
  {  // self term
    uint2 v = g8[(size_t)node * 16 + sl];
    floatx2 p0 = __builtin_amdgcn_cvt_pk_f32_fp8((int)v.x, false);
    floatx2 p1 = __builtin_amdgcn_cvt_pk_f32_fp8((int)v.x, true);
    floatx2 p2 = __builtin_amdgcn_cvt_pk_f32_fp8((int)v.y, false);
    floatx2 p3 = __builtin_amdgcn_cvt_pk_f32_fp8((int)v.y, true);
    acc[0] = p0.x; acc[1] = p0.y; acc[2] = p1.x; acc[3] = p1.y;
    acc[4] = p2.x; acc[5] = p2.y; acc[6] = p3.x; acc[7] = p3.y;
  }
  int i = s;
  for (; i + 8 <= e; i += 8) {
    int r0 = csr_row[i];
    int r1 = csr_row[i + 1];
    int r2 = csr_row[i + 2];
    int r3 = csr_row[i + 3];
    int r4 = csr_row[i + 4];
    int r5 = csr_row[i + 5];
    int r6 = csr_row[i + 6];
    int r7 = csr_row[i + 7];
    uint2 v0 = g8[(size_t)r0 * 16 + sl];
    uint2 v1 = g8[(size_t)r1 * 16 + sl];
    uint2 v2 = g8[(size_t)r2 * 16 + sl];
    uint2 v3 = g8[(size_t)r3 * 16 + sl];
    uint2 v4 = g8[(size_t)r4 * 16 + sl];
    uint2 v5 = g8[(size_t)r5 * 16 + sl];
    uint2 v6 = g8[(size_t)r6 * 16 + sl];
    uint2 v7 = g8[(size_t)r7 * 16 + sl];
    add8_fp8(acc, v0);
    add8_fp8(acc, v1);
    add8_fp8(acc, v2);
    add8_fp8(acc, v3);
    add8_fp8(acc, v4);
    add8_fp8(acc, v5);
    add8_fp8(acc, v6);
    add8_fp8(acc, v7);
  }
  for (; i + 4 <= e; i += 4) {
    int r0 = csr_row[i];
    int r1 = csr_row[i + 1];
    int r2 = csr_row[i + 2];
    int r3 = csr_row[i + 3];
    uint2 v0 = g8[(size_t)r0 * 16 + sl];
    uint2 v1 = g8[(size_t)r1 * 16 + sl];
    uint2 v2 = g8[(size_t)r2 * 16 + sl];
    uint2 v3 = g8[(size_t)r3 * 16 + sl];
    add8_fp8(acc, v0);
    add8_fp8(acc, v1);
    add8_fp8(acc, v2);
    add8_fp8(acc, v3);
  }
  for (; i < e; i++) {
    uint2 v = g8[(size_t)csr_row[i] * 16 + sl];
    add8_fp8(acc, v);
  }
  float dn = dinv[node];
#pragma unroll
  for (int q = 0; q < 8; q++) acc[q] *= dn;
  if (bias) {
    const float4* b4 = (const float4*)(bias + sl * 8);
    float4 b0 = b4[0], b1 = b4[1];
    acc[0] += b0.x; acc[1] += b0.y; acc[2] += b0.z; acc[3] += b0.w;
    acc[4] += b1.x; acc[5] += b1.y; acc[6] += b1.z; acc[7] += b1.w;
  }
  if (relu) {
#pragma unroll
    for (int q = 0; q < 8; q++) acc[q] = fmaxf(acc[q], 0.f);
  }
  if (scale_out) {
#pragma unroll
    for (int q = 0; q < 8; q++) acc[q] *= dn;
  }
  union { uint4 u; __half2 h[4]; } ov;
#pragma unroll
  for (int q = 0; q < 4; q++)
    ov.h[q] = __floats2half2_rn(acc[2 * q], acc[2 * q + 1]);
  out16[(size_t)node * 16 + sl] = ov.u;
}

// --- Agg (fp16 input): unchanged R15 path, used for the layer-4 agg ---------
__device__ __forceinline__ void add8(float* acc, uint4 r) {
  union { uint4 u; __half2 h[4]; } cv;
  cv.u = r;
#pragma unroll
  for (int q = 0; q < 4; q++) {
    float2 v = __half22float2(cv.h[q]);
    acc[2 * q] += v.x;
    acc[2 * q + 1] += v.y;
  }
}

__global__ __launch_bounds__(256) void k_agg(const uint4* __restrict__ h16,
                                             const int* __restrict__ offs,
                                             const int* __restrict__ csr_row,
                                             const float* __restrict__ dinv,
                                             const float* __restrict__ bias,
                                             uint4* __restrict__ out16,
                                             int n, int relu, int scale_out) {
  int t = threadIdx.x;
  int wave = t >> 6, l = t & 63;
  int g = l >> 4, sl = l & 15;
  int node = blockIdx.x * 16 + wave * 4 + g;
  if (node >= n) return;
  int s = offs[node], e = offs[node + 1];
  float acc[8];
  {  // self term
    uint4 r = h16[(size_t)node * 16 + sl];
    union { uint4 u; __half2 h[4]; } cv;
    cv.u = r;
#pragma unroll
    for (int q = 0; q < 4; q++) {
      float2 v = __half22float2(cv.h[q]);
      acc[2 * q] = v.x;
      acc[2 * q + 1] = v.y;
    }
  }
  int i = s;
  for (; i + 8 <= e; i += 8) {
    int r0 = csr_row[i];
    int r1 = csr_row[i + 1];
    int r2 = csr_row[i + 2];
    int r3 = csr_row[i + 3];
    int r4 = csr_row[i + 4];
    int r5 = csr_row[i + 5];
    int r6 = csr_row[i + 6];
    int r7 = csr_row[i + 7];
    uint4 v0 = h16[(size_t)r0 * 16 + sl];
    uint4 v1 = h16[(size_t)r1 * 16 + sl];
    uint4 v2 = h16[(size_t)r2 * 16 + sl];
    uint4 v3 = h16[(size_t)r3 * 16 + sl];
    uint4 v4 = h16[(size_t)r4 * 16 + sl];
    uint4 v5 = h16[(size_t)r5 * 16 + sl];
    uint4 v6 = h16[(size_t)r6 * 16 + sl];
    uint4 v7 = h16[(size_t)r7 * 16 + sl];
    add8(acc, v0);
    add8(acc, v1);
    add8(acc, v2);
    add8(acc, v3);
    add8(acc, v4);
    add8(acc, v5);
    add8(acc, v6);
    add8(acc, v7);
  }
  for (; i + 4 <= e; i += 4) {
    int r0 = csr_row[i];
    int r1 = csr_row[i + 1];
    int r2 = csr_row[i + 2];
    int r3 = csr_row[i + 3];
    uint4 v0 = h16[(size_t)r0 * 16 + sl];
    uint4 v1 = h16[(size_t)r1 * 16 + sl];
    uint4 v2 = h16[(size_t)r2 * 16 + sl];
    uint4 v3 = h16[(size_t)r3 * 16 + sl];
    add8(acc, v0);
    add8(acc, v1);
    add8(acc, v2);
    add8(acc, v3);
  }
  for (; i < e; i++) {
    uint4 v = h16[(size_t)csr_row[i] * 16 + sl];
    add8(acc, v);
  }
  float dn = dinv[node];
#pragma unroll
  for (int q = 0; q < 8; q++) acc[q] *= dn;
  if (bias) {
    const float4* b4 = (const float4*)(bias + sl * 8);
    float4 b0 = b4[0], b1 = b4[1];
    acc[0] += b0.x; acc[1] += b0.y; acc[2] += b0.z; acc[3] += b0.w;
    acc[4] += b1.x; acc[5] += b1.y; acc[6] += b1.z; acc[7] += b1.w;
  }
  if (relu) {
#pragma unroll
    for (int q = 0; q < 8; q++) acc[q] = fmaxf(acc[q], 0.f);
  }
  if (scale_out) {
#pragma unroll
    for (int q = 0; q < 8; q++) acc[q] *= dn;
  }
  union { uint4 u; __half2 h[4]; } ov;
#pragma unroll
  for (int q = 0; q < 4; q++)
    ov.h[q] = __floats2half2_rn(acc[2 * q], acc[2 * q + 1]);
  out16[(size_t)node * 16 + sl] = ov.u;
}

// --- Mean pool (fp16 input): chunked partial sums + atomics -----------------
#define POOL_CH 64
__global__ __launch_bounds__(128) void k_pool_partial(
    const _Float16* __restrict__ h, const void* __restrict__ batch, int n,
    float* __restrict__ sums, float* __restrict__ cnts,
    const int* __restrict__ flag) {
  int start = blockIdx.x * POOL_CH;
  if (start >= n) return;
  int end = start + POOL_CH;
  if (end > n) end = n;
  int f = threadIdx.x;  // 128 feature lanes
  int is64 = *flag;
  int g = idx_at(batch, start, is64);
  float acc = 0.f, c = 0.f;
  for (int i = start; i < end; i++) {
    int gi = idx_at(batch, i, is64);
    if (gi != g) {
      atomicAdd(&sums[g * 128 + f], acc);
      if (f == 0) atomicAdd(&cnts[g], c);
      acc = 0.f; c = 0.f; g = gi;
    }
    acc += (float)h[(size_t)i * 128 + f];
    c += 1.f;
  }
  atomicAdd(&sums[g * 128 + f], acc);
  if (f == 0) atomicAdd(&cnts[g], c);
}

// pooled = sums/cnt; t1 = pooled@W3+b3; logits = t1@Wlin+blin; softmax.
__global__ __launch_bounds__(128) void k_final(const float* __restrict__ sums,
                                               const float* __restrict__ cnts,
                                               const float* __restrict__ W3,
                                               const float* __restrict__ b3,
                                               const float* __restrict__ Wlin,
                                               const float* __restrict__ blin,
                                               float* __restrict__ out) {
  __shared__ float p[128];
  __shared__ float t1[128];
  __shared__ float lg[16];
  int g = blockIdx.x;
  int t = threadIdx.x;
  float inv = 1.f / fmaxf(cnts[g], 1.f);
  p[t] = sums[g * 128 + t] * inv;
  __syncthreads();
  float acc = 0.f;
  for (int k = 0; k < 128; k++) acc += p[k] * W3[k * 128 + t];
  t1[t] = acc + b3[t];
  __syncthreads();
  if (t < 16) {
    float a2 = 0.f;
    for (int k = 0; k < 128; k++) a2 += t1[k] * Wlin[k * 16 + t];
    lg[t] = a2 + blin[t];
  }
  __syncthreads();
  if (t < 16) {
    float m = -1e30f;
    for (int j = 0; j < 16; j++) m = fmaxf(m, lg[j]);
    float s = 0.f;
    for (int j = 0; j < 16; j++) s += expf(lg[j] - m);
    out[g * 16 + t] = expf(lg[t] - m) / s;
  }
}

extern "C" void kernel_launch(void* const* d_in, const int* in_sizes, int n_in,
                              void* d_out, int out_size, void* d_ws, size_t ws_size,
                              hipStream_t stream) {
  const float* x = (const float*)d_in[0];
  const void* edge = d_in[1];
  const void* batch = d_in[2];
  const float* W[4] = {(const float*)d_in[3], (const float*)d_in[5],
                       (const float*)d_in[7], (const float*)d_in[9]};
  const float* b[4] = {(const float*)d_in[4], (const float*)d_in[6],
                       (const float*)d_in[8], (const float*)d_in[10]};
  const float* Wlin = (const float*)d_in[11];
  const float* blin = (const float*)d_in[12];
  float* out = (float*)d_out;

  int n = in_sizes[0] / 128;
  int E = in_sizes[1] / 2;
  int ngraphs = out_size / 16;

  char* ws = (char*)d_ws;
  size_t off = 0;
  auto alloc = [&](size_t bytes) -> void* {
    void* p = ws + off;
    off = (off + bytes + 255) & ~(size_t)255;
    return p;
  };
  int* flag = (int*)alloc(4);
  int* cnt = (int*)alloc((size_t)n * 4);
  int* offs = (int*)alloc((size_t)(n + 1) * 4);
  int* cursor = (int*)alloc((size_t)n * 4);
  float* dinv = (float*)alloc((size_t)n * 4);
  int* bsum = (int*)alloc(1024 * 4);
  int* csr_row = (int*)alloc((size_t)E * 4);
  _Float16* Wp0 = (_Float16*)alloc(16384 * 2);
  _Float16* Wp1 = (_Float16*)alloc(16384 * 2);
  _Float16* Wp2 = (_Float16*)alloc(16384 * 2);
  unsigned char* g8 = (unsigned char*)alloc((size_t)n * 128);  // gemm out (fp8)
  _Float16* hB = (_Float16*)alloc((size_t)n * 128 * 2);  // agg0-2 out (gemm A)
  _Float16* hC = (_Float16*)alloc((size_t)n * 128 * 2);  // agg4 out (pool in)
  float* sums = (float*)alloc((size_t)ngraphs * 128 * 4);
  float* cnts = (float*)alloc((size_t)ngraphs * 4);

  hipMemsetAsync(cnt, 0, (size_t)n * 4, stream);
  hipMemsetAsync(sums, 0, (size_t)ngraphs * 128 * 4, stream);
  hipMemsetAsync(cnts, 0, (size_t)ngraphs * 4, stream);
  k_detect<<<1, 64, 0, stream>>>((const int*)edge, flag);
  k_count<<<(E + 255) / 256, 256, 0, stream>>>(edge, E, cnt, flag);
  k_dinv<<<(n + 255) / 256, 256, 0, stream>>>(cnt, n, dinv);
  int nb = (n + 255) / 256;
  k_scan1<<<nb, 256, 0, stream>>>(cnt, offs, bsum, n);
  k_scan2<<<1, 256, 0, stream>>>(bsum, nb);
  k_scan3<<<nb, 256, 0, stream>>>(offs, cursor, bsum, n, E);
  int nchunks = (E + FILL_CH - 1) / FILL_CH;
  k_fill<<<nchunks * 8, 256, 0, stream>>>(edge, E, n, cursor, csr_row, flag);
  k_wprep3<<<192, 256, 0, stream>>>(W[0], W[1], W[2], Wp0, Wp1, Wp2);

  int ngb = (n + 63) / 64;     // gemm blocks (64 rows each)
  int nagg = (n + 15) / 16;    // agg blocks (16 nodes each)
  // layer 0 (A = x fp32, converted in-register)
  k_gemm16<<<ngb, 256, 0, stream>>>(nullptr, x, Wp0, dinv, g8, n);
  k_agg_fp8<<<nagg, 256, 0, stream>>>((const uint2*)g8, offs, csr_row, dinv,
                                      b[0], (uint4*)hB, n, 1, 0);
  // layer 1
  k_gemm16<<<ngb, 256, 0, stream>>>(hB, nullptr, Wp1, dinv, g8, n);
  k_agg_fp8<<<nagg, 256, 0, stream>>>((const uint2*)g8, offs, csr_row, dinv,
                                      b[1], (uint4*)hB, n, 1, 0);
  // layer 2: output h3 consumed only by the layer-4 agg -> pre-scale by dinv
  k_gemm16<<<ngb, 256, 0, stream>>>(hB, nullptr, Wp2, dinv, g8, n);
  k_agg_fp8<<<nagg, 256, 0, stream>>>((const uint2*)g8, offs, csr_row, dinv,
                                      b[2], (uint4*)hB, n, 1, 1);
  // layer 4 agg (fp16 gather; no bias/relu); W3+b3 applied post-pool in k_final
  k_agg<<<nagg, 256, 0, stream>>>((const uint4*)hB, offs, csr_row, dinv,
                                  nullptr, (uint4*)hC, n, 0, 0);
  k_pool_partial<<<(n + POOL_CH - 1) / POOL_CH, 128, 0, stream>>>(hC, batch, n, sums, cnts, flag);
  k_final<<<ngraphs, 128, 0, stream>>>(sums, cnts, W[3], b[3], Wlin, blin, out);
}

// Round 17
// 218.490 us; speedup vs baseline: 1.2972x; 1.0510x over previous
//
#include <hip/hip_runtime.h>
#include <hip/hip_fp16.h>

// ---------------------------------------------------------------------------
// GCN forward. Key transforms (cumulative):
//  - dinv folded into features; CSR stores only the 4B source row.
//  - XCD-windowed CSR fill (one XCD owns each CSR slice -> stores merge in L2).
//  - W3 commuted past the mean pool (layer-4 GEMM eliminated).
//  - MFMA fp16 GEMMs, fp32 accumulation everywhere.
//  - ALL four gathered arrays stored FP8 e4m3 (R16: gemm outputs; R17: also
//    the l=2 agg output consumed by the layer-4 agg). Gather traffic halved
//    twice; absmax budget ~6e-4 vs threshold 1.43e-3.
//  - dinv computation folded into scan1 (launch-count trim).
// ---------------------------------------------------------------------------

typedef _Float16 half8 __attribute__((ext_vector_type(8)));
typedef float f32x4 __attribute__((ext_vector_type(4)));
typedef float floatx2 __attribute__((ext_vector_type(2)));

__device__ __forceinline__ int idx_at(const void* p, long long i, int is64) {
  return is64 ? (int)((const long long*)p)[i] : ((const int*)p)[i];
}

__global__ void k_detect(const int* __restrict__ edge, int* __restrict__ flag) {
  if (threadIdx.x == 0 && blockIdx.x == 0) {
    int all0 = 1;
    for (int i = 1; i < 128; i += 2)
      if (edge[i] != 0) { all0 = 0; break; }
    *flag = all0;
  }
}

__global__ void k_count(const void* __restrict__ edge, int E,
                        int* __restrict__ cnt, const int* __restrict__ flag) {
  int e = blockIdx.x * 256 + threadIdx.x;
  int is64 = *flag;
  if (e < E) {
    int c = idx_at(edge, (long long)E + e, is64);  // col = target
    atomicAdd(&cnt[c], 1);
  }
}

// --- scan1 (+ dinv fused): exclusive scan chunk + rsqrt ----------------------
__global__ void k_scan1(const int* __restrict__ cnt, int* __restrict__ offs,
                        int* __restrict__ bsum, float* __restrict__ dinv, int n) {
  __shared__ int lds[256];
  int i = blockIdx.x * 256 + threadIdx.x;
  int v = (i < n) ? cnt[i] : 0;
  if (i < n) dinv[i] = rsqrtf((float)(v + 1));  // +1 self loop
  lds[threadIdx.x] = v;
  __syncthreads();
  for (int off = 1; off < 256; off <<= 1) {
    int t = (threadIdx.x >= off) ? lds[threadIdx.x - off] : 0;
    __syncthreads();
    lds[threadIdx.x] += t;
    __syncthreads();
  }
  if (i < n) offs[i] = lds[threadIdx.x] - v;
  if (threadIdx.x == 255) bsum[blockIdx.x] = lds[255];
}

__global__ void k_scan2(int* __restrict__ bsum, int nb) {
  __shared__ int lds[256];
  int v = (threadIdx.x < nb) ? bsum[threadIdx.x] : 0;
  lds[threadIdx.x] = v;
  __syncthreads();
  for (int off = 1; off < 256; off <<= 1) {
    int t = (threadIdx.x >= off) ? lds[threadIdx.x - off] : 0;
    __syncthreads();
    lds[threadIdx.x] += t;
    __syncthreads();
  }
  if (threadIdx.x < nb) bsum[threadIdx.x] = lds[threadIdx.x] - v;
}

__global__ void k_scan3(int* __restrict__ offs, int* __restrict__ cursor,
                        const int* __restrict__ bsum, int n, int E) {
  int i = blockIdx.x * 256 + threadIdx.x;
  if (i < n) {
    int o = offs[i] + bsum[blockIdx.x];
    offs[i] = o;
    cursor[i] = o;
  }
  if (i == 0) offs[n] = E;
}

// XCD-windowed CSR fill: block b -> edge chunk (b>>3), target window (b&7).
#define FILL_CH 4096
__global__ __launch_bounds__(256) void k_fill(const void* __restrict__ edge, int E,
                                              int n,
                                              int* __restrict__ cursor,
                                              int* __restrict__ csr_row,
                                              const int* __restrict__ flag) {
  int w = blockIdx.x & 7;
  int chunk = blockIdx.x >> 3;
  int lo = (int)(((long long)w * n) >> 3);
  int hi = (int)(((long long)(w + 1) * n) >> 3);
  int s = chunk * FILL_CH;
  int e_end = s + FILL_CH;
  if (e_end > E) e_end = E;
  int is64 = *flag;
  for (int e = s + threadIdx.x; e < e_end; e += 256) {
    int c = idx_at(edge, (long long)E + e, is64);
    if (c >= lo && c < hi) {
      int r = idx_at(edge, e, is64);
      int p = atomicAdd(&cursor[c], 1);
      csr_row[p] = r;
    }
  }
}

// --- W repack x3: fp32 [k][c] -> fp16 fragment order (one launch) -----------
__global__ void k_wprep3(const float* __restrict__ W0, const float* __restrict__ W1,
                         const float* __restrict__ W2, _Float16* __restrict__ P0,
                         _Float16* __restrict__ P1, _Float16* __restrict__ P2) {
  int t = blockIdx.x * 256 + threadIdx.x;  // 0..49151
  int which = t >> 14;
  int u = t & 16383;
  const float* W = which == 0 ? W0 : (which == 1 ? W1 : W2);
  _Float16* Wp = which == 0 ? P0 : (which == 1 ? P1 : P2);
  int k = u >> 7, c = u & 127;
  int cb = c >> 4, cl = c & 15, ks = k >> 5, kk = k & 31;
  int lane = (kk >> 3) * 16 + cl, j = kk & 7;
  Wp[((cb * 4 + ks) * 64 + lane) * 8 + j] = (_Float16)W[u];
}

// --- MFMA GEMM: C8[r] = fp8_e4m3((A[r] @ W) * dinv[r]) ----------------------
__global__ __launch_bounds__(256) void k_gemm16(const _Float16* __restrict__ A16,
                                                const float* __restrict__ A32,
                                                const _Float16* __restrict__ Wp,
                                                const float* __restrict__ dinv,
                                                unsigned char* __restrict__ C8,
                                                int n) {
  __shared__ float4 Wl[2048];  // 32 KB prepped W
  int t = threadIdx.x;
  const float4* Wp4 = (const float4*)Wp;
#pragma unroll
  for (int i = 0; i < 8; i++) Wl[t + 256 * i] = Wp4[t + 256 * i];
  __syncthreads();
  int wave = t >> 6, l = t & 63;
  int m = blockIdx.x * 64 + wave * 16;
  int lr = l & 15, lg = l >> 4;
  int arow = m + lr;
  if (arow > n - 1) arow = n - 1;  // clamp: stores guarded below
  half8 a[4];
  if (A16) {
#pragma unroll
    for (int ks = 0; ks < 4; ks++)
      a[ks] = *(const half8*)(A16 + (size_t)arow * 128 + ks * 32 + lg * 8);
  } else {
#pragma unroll
    for (int ks = 0; ks < 4; ks++) {
      const float4* s = (const float4*)(A32 + (size_t)arow * 128 + ks * 32 + lg * 8);
      float4 s0 = s[0], s1 = s[1];
      half8 v;
      v[0] = (_Float16)s0.x; v[1] = (_Float16)s0.y;
      v[2] = (_Float16)s0.z; v[3] = (_Float16)s0.w;
      v[4] = (_Float16)s1.x; v[5] = (_Float16)s1.y;
      v[6] = (_Float16)s1.z; v[7] = (_Float16)s1.w;
      a[ks] = v;
    }
  }
  const half8* WlH = (const half8*)Wl;
  f32x4 acc[8];
#pragma unroll
  for (int cb = 0; cb < 8; cb++) {
    f32x4 c = {0.f, 0.f, 0.f, 0.f};
#pragma unroll
    for (int ks = 0; ks < 4; ks++) {
      half8 bfrag = WlH[(cb * 4 + ks) * 64 + l];
      c = __builtin_amdgcn_mfma_f32_16x16x32_f16(a[ks], bfrag, c, 0, 0, 0);
    }
    acc[cb] = c;
  }
#pragma unroll
  for (int i = 0; i < 4; i++) {
    int r = m + lg * 4 + i;
    if (r < n) {
      float sc = dinv[r];
#pragma unroll
      for (int cb = 0; cb < 8; cb++) {
        float v = acc[cb][i] * sc;
        unsigned int pk = __builtin_amdgcn_cvt_pk_fp8_f32(v, v, 0, false);
        C8[(size_t)r * 128 + cb * 16 + lr] = (unsigned char)(pk & 0xff);
      }
    }
  }
}

// --- Agg (fp8 gather): 4 nodes/wave, 16 lanes/node, 8B/lane, 8-deep ---------
// Input contract: g8[r] already carries its dinv[r] (from GEMM epi or scale_out).
// Exactly one of out16/out8 is non-null.
__device__ __forceinline__ void add8_fp8(float* acc, uint2 v) {
  floatx2 p0 = __builtin_amdgcn_cvt_pk_f32_fp8((int)v.x, false);
  floatx2 p1 = __builtin_amdgcn_cvt_pk_f32_fp8((int)v.x, true);
  floatx2 p2 = __builtin_amdgcn_cvt_pk_f32_fp8((int)v.y, false);
  floatx2 p3 = __builtin_amdgcn_cvt_pk_f32_fp8((int)v.y, true);
  acc[0] += p0.x; acc[1] += p0.y; acc[2] += p1.x; acc[3] += p1.y;
  acc[4] += p2.x; acc[5] += p2.y; acc[6] += p3.x; acc[7] += p3.y;
}

__global__ __launch_bounds__(256) void k_agg_fp8(const uint2* __restrict__ g8,
                                                 const int* __restrict__ offs,
                                                 const int* __restrict__ csr_row,
                                                 const float* __restrict__ dinv,
                                                 const float* __restrict__ bias,
                                                 uint4* __restrict__ out16,
                                                 uint2* __restrict__ out8,
                                                 int n, int relu, int scale_out) {
  int t = threadIdx.x;
  int wave = t >> 6, l = t & 63;
  int g = l >> 4, sl = l & 15;
  int node = blockIdx.x * 16 + wave * 4 + g;
  if (node >= n) return;
  int s = offs[node], e = offs[node + 1];
  float acc[8];
  {  // self term
    uint2 v = g8[(size_t)node * 16 + sl];
    floatx2 p0 = __builtin_amdgcn_cvt_pk_f32_fp8((int)v.x, false);
    floatx2 p1 = __builtin_amdgcn_cvt_pk_f32_fp8((int)v.x, true);
    floatx2 p2 = __builtin_amdgcn_cvt_pk_f32_fp8((int)v.y, false);
    floatx2 p3 = __builtin_amdgcn_cvt_pk_f32_fp8((int)v.y, true);
    acc[0] = p0.x; acc[1] = p0.y; acc[2] = p1.x; acc[3] = p1.y;
    acc[4] = p2.x; acc[5] = p2.y; acc[6] = p3.x; acc[7] = p3.y;
  }
  int i = s;
  for (; i + 8 <= e; i += 8) {
    int r0 = csr_row[i];
    int r1 = csr_row[i + 1];
    int r2 = csr_row[i + 2];
    int r3 = csr_row[i + 3];
    int r4 = csr_row[i + 4];
    int r5 = csr_row[i + 5];
    int r6 = csr_row[i + 6];
    int r7 = csr_row[i + 7];
    uint2 v0 = g8[(size_t)r0 * 16 + sl];
    uint2 v1 = g8[(size_t)r1 * 16 + sl];
    uint2 v2 = g8[(size_t)r2 * 16 + sl];
    uint2 v3 = g8[(size_t)r3 * 16 + sl];
    uint2 v4 = g8[(size_t)r4 * 16 + sl];
    uint2 v5 = g8[(size_t)r5 * 16 + sl];
    uint2 v6 = g8[(size_t)r6 * 16 + sl];
    uint2 v7 = g8[(size_t)r7 * 16 + sl];
    add8_fp8(acc, v0);
    add8_fp8(acc, v1);
    add8_fp8(acc, v2);
    add8_fp8(acc, v3);
    add8_fp8(acc, v4);
    add8_fp8(acc, v5);
    add8_fp8(acc, v6);
    add8_fp8(acc, v7);
  }
  for (; i + 4 <= e; i += 4) {
    int r0 = csr_row[i];
    int r1 = csr_row[i + 1];
    int r2 = csr_row[i + 2];
    int r3 = csr_row[i + 3];
    uint2 v0 = g8[(size_t)r0 * 16 + sl];
    uint2 v1 = g8[(size_t)r1 * 16 + sl];
    uint2 v2 = g8[(size_t)r2 * 16 + sl];
    uint2 v3 = g8[(size_t)r3 * 16 + sl];
    add8_fp8(acc, v0);
    add8_fp8(acc, v1);
    add8_fp8(acc, v2);
    add8_fp8(acc, v3);
  }
  for (; i < e; i++) {
    uint2 v = g8[(size_t)csr_row[i] * 16 + sl];
    add8_fp8(acc, v);
  }
  float dn = dinv[node];
#pragma unroll
  for (int q = 0; q < 8; q++) acc[q] *= dn;
  if (bias) {
    const float4* b4 = (const float4*)(bias + sl * 8);
    float4 b0 = b4[0], b1 = b4[1];
    acc[0] += b0.x; acc[1] += b0.y; acc[2] += b0.z; acc[3] += b0.w;
    acc[4] += b1.x; acc[5] += b1.y; acc[6] += b1.z; acc[7] += b1.w;
  }
  if (relu) {
#pragma unroll
    for (int q = 0; q < 8; q++) acc[q] = fmaxf(acc[q], 0.f);
  }
  if (scale_out) {
#pragma unroll
    for (int q = 0; q < 8; q++) acc[q] *= dn;
  }
  if (out16) {
    union { uint4 u; __half2 h[4]; } ov;
#pragma unroll
    for (int q = 0; q < 4; q++)
      ov.h[q] = __floats2half2_rn(acc[2 * q], acc[2 * q + 1]);
    out16[(size_t)node * 16 + sl] = ov.u;
  } else {
    unsigned int w0 = __builtin_amdgcn_cvt_pk_fp8_f32(acc[0], acc[1], 0, false);
    w0 = __builtin_amdgcn_cvt_pk_fp8_f32(acc[2], acc[3], w0, true);
    unsigned int w1 = __builtin_amdgcn_cvt_pk_fp8_f32(acc[4], acc[5], 0, false);
    w1 = __builtin_amdgcn_cvt_pk_fp8_f32(acc[6], acc[7], w1, true);
    out8[(size_t)node * 16 + sl] = uint2{w0, w1};
  }
}

// --- Mean pool (fp16 input): chunked partial sums + atomics -----------------
#define POOL_CH 64
__global__ __launch_bounds__(128) void k_pool_partial(
    const _Float16* __restrict__ h, const void* __restrict__ batch, int n,
    float* __restrict__ sums, float* __restrict__ cnts,
    const int* __restrict__ flag) {
  int start = blockIdx.x * POOL_CH;
  if (start >= n) return;
  int end = start + POOL_CH;
  if (end > n) end = n;
  int f = threadIdx.x;  // 128 feature lanes
  int is64 = *flag;
  int g = idx_at(batch, start, is64);
  float acc = 0.f, c = 0.f;
  for (int i = start; i < end; i++) {
    int gi = idx_at(batch, i, is64);
    if (gi != g) {
      atomicAdd(&sums[g * 128 + f], acc);
      if (f == 0) atomicAdd(&cnts[g], c);
      acc = 0.f; c = 0.f; g = gi;
    }
    acc += (float)h[(size_t)i * 128 + f];
    c += 1.f;
  }
  atomicAdd(&sums[g * 128 + f], acc);
  if (f == 0) atomicAdd(&cnts[g], c);
}

// pooled = sums/cnt; t1 = pooled@W3+b3; logits = t1@Wlin+blin; softmax.
__global__ __launch_bounds__(128) void k_final(const float* __restrict__ sums,
                                               const float* __restrict__ cnts,
                                               const float* __restrict__ W3,
                                               const float* __restrict__ b3,
                                               const float* __restrict__ Wlin,
                                               const float* __restrict__ blin,
                                               float* __restrict__ out) {
  __shared__ float p[128];
  __shared__ float t1[128];
  __shared__ float lg[16];
  int g = blockIdx.x;
  int t = threadIdx.x;
  float inv = 1.f / fmaxf(cnts[g], 1.f);
  p[t] = sums[g * 128 + t] * inv;
  __syncthreads();
  float acc = 0.f;
  for (int k = 0; k < 128; k++) acc += p[k] * W3[k * 128 + t];
  t1[t] = acc + b3[t];
  __syncthreads();
  if (t < 16) {
    float a2 = 0.f;
    for (int k = 0; k < 128; k++) a2 += t1[k] * Wlin[k * 16 + t];
    lg[t] = a2 + blin[t];
  }
  __syncthreads();
  if (t < 16) {
    float m = -1e30f;
    for (int j = 0; j < 16; j++) m = fmaxf(m, lg[j]);
    float s = 0.f;
    for (int j = 0; j < 16; j++) s += expf(lg[j] - m);
    out[g * 16 + t] = expf(lg[t] - m) / s;
  }
}

extern "C" void kernel_launch(void* const* d_in, const int* in_sizes, int n_in,
                              void* d_out, int out_size, void* d_ws, size_t ws_size,
                              hipStream_t stream) {
  const float* x = (const float*)d_in[0];
  const void* edge = d_in[1];
  const void* batch = d_in[2];
  const float* W[4] = {(const float*)d_in[3], (const float*)d_in[5],
                       (const float*)d_in[7], (const float*)d_in[9]};
  const float* b[4] = {(const float*)d_in[4], (const float*)d_in[6],
                       (const float*)d_in[8], (const float*)d_in[10]};
  const float* Wlin = (const float*)d_in[11];
  const float* blin = (const float*)d_in[12];
  float* out = (float*)d_out;

  int n = in_sizes[0] / 128;
  int E = in_sizes[1] / 2;
  int ngraphs = out_size / 16;

  char* ws = (char*)d_ws;
  size_t off = 0;
  auto alloc = [&](size_t bytes) -> void* {
    void* p = ws + off;
    off = (off + bytes + 255) & ~(size_t)255;
    return p;
  };
  int* flag = (int*)alloc(4);
  int* cnt = (int*)alloc((size_t)n * 4);
  int* offs = (int*)alloc((size_t)(n + 1) * 4);
  int* cursor = (int*)alloc((size_t)n * 4);
  float* dinv = (float*)alloc((size_t)n * 4);
  int* bsum = (int*)alloc(1024 * 4);
  int* csr_row = (int*)alloc((size_t)E * 4);
  _Float16* Wp0 = (_Float16*)alloc(16384 * 2);
  _Float16* Wp1 = (_Float16*)alloc(16384 * 2);
  _Float16* Wp2 = (_Float16*)alloc(16384 * 2);
  unsigned char* g8 = (unsigned char*)alloc((size_t)n * 128);   // gemm out (fp8)
  unsigned char* g8b = (unsigned char*)alloc((size_t)n * 128);  // agg2 out (fp8)
  _Float16* hB = (_Float16*)alloc((size_t)n * 128 * 2);  // agg0/1 out (gemm A)
  _Float16* hC = (_Float16*)alloc((size_t)n * 128 * 2);  // agg4 out (pool in)
  float* sums = (float*)alloc((size_t)ngraphs * 128 * 4);
  float* cnts = (float*)alloc((size_t)ngraphs * 4);

  hipMemsetAsync(cnt, 0, (size_t)n * 4, stream);
  hipMemsetAsync(sums, 0, (size_t)ngraphs * 128 * 4, stream);
  hipMemsetAsync(cnts, 0, (size_t)ngraphs * 4, stream);
  k_detect<<<1, 64, 0, stream>>>((const int*)edge, flag);
  k_count<<<(E + 255) / 256, 256, 0, stream>>>(edge, E, cnt, flag);
  int nb = (n + 255) / 256;
  k_scan1<<<nb, 256, 0, stream>>>(cnt, offs, bsum, dinv, n);
  k_scan2<<<1, 256, 0, stream>>>(bsum, nb);
  k_scan3<<<nb, 256, 0, stream>>>(offs, cursor, bsum, n, E);
  int nchunks = (E + FILL_CH - 1) / FILL_CH;
  k_fill<<<nchunks * 8, 256, 0, stream>>>(edge, E, n, cursor, csr_row, flag);
  k_wprep3<<<192, 256, 0, stream>>>(W[0], W[1], W[2], Wp0, Wp1, Wp2);

  int ngb = (n + 63) / 64;     // gemm blocks (64 rows each)
  int nagg = (n + 15) / 16;    // agg blocks (16 nodes each)
  // layer 0 (A = x fp32, converted in-register)
  k_gemm16<<<ngb, 256, 0, stream>>>(nullptr, x, Wp0, dinv, g8, n);
  k_agg_fp8<<<nagg, 256, 0, stream>>>((const uint2*)g8, offs, csr_row, dinv,
                                      b[0], (uint4*)hB, nullptr, n, 1, 0);
  // layer 1
  k_gemm16<<<ngb, 256, 0, stream>>>(hB, nullptr, Wp1, dinv, g8, n);
  k_agg_fp8<<<nagg, 256, 0, stream>>>((const uint2*)g8, offs, csr_row, dinv,
                                      b[1], (uint4*)hB, nullptr, n, 1, 0);
  // layer 2: fp8 output pre-scaled by dinv (consumer = layer-4 agg)
  k_gemm16<<<ngb, 256, 0, stream>>>(hB, nullptr, Wp2, dinv, g8, n);
  k_agg_fp8<<<nagg, 256, 0, stream>>>((const uint2*)g8, offs, csr_row, dinv,
                                      b[2], nullptr, (uint2*)g8b, n, 1, 1);
  // layer 4 agg (fp8 gather; no bias/relu); W3+b3 applied post-pool in k_final
  k_agg_fp8<<<nagg, 256, 0, stream>>>((const uint2*)g8b, offs, csr_row, dinv,
                                      nullptr, (uint4*)hC, nullptr, n, 0, 0);
  k_pool_partial<<<(n + POOL_CH - 1) / POOL_CH, 128, 0, stream>>>(hC, batch, n, sums, cnts, flag);
  k_final<<<ngraphs, 128, 0, stream>>>(sums, cnts, W[3], b[3], Wlin, blin, out);
}